// Round 4
// baseline (794.585 us; speedup 1.0000x reference)
//
#include <hip/hip_runtime.h>

// WindowAttention: B_=4096, N=49, C=256, H=8, hd=32, nW=64
// ws layout (bf16): [q | k | v | pre] each SEG elements
//   q/k/v: plain (M=200704, 256) row-major, m = b*49+i, c = h*32+d
//          (GEMM-natural layout; q pre-scaled by hd^-0.5)
//   pre  : (B_, N, C) attention output before proj
// d_out doubles as scratch:
//   [0, 8.39MB)  : expanded (mask+bias) ADD tensor (nW*H, 64, 64) fp32
//   [10MB, ...)  : qkv_w converted to bf16 (768x256)
//   [16MB, ...)  : x converted to bf16 (200704x256, 102.8MB)
// proj_gemm fully overwrites d_out afterwards and reads none of it.
// proj_w (bf16) is converted AFTER attn into ws segment 0 (q, dead by then).
#define SEG 51380224  // 4096*8*49*32 == 4096*49*256

typedef __attribute__((ext_vector_type(8))) __bf16 bf16x8;
typedef __attribute__((ext_vector_type(4))) __bf16 bf16x4;
typedef __attribute__((ext_vector_type(4))) float f32x4;

static __device__ __forceinline__ bf16x8 bzero8() {
    bf16x8 z;
#pragma unroll
    for (int u = 0; u < 8; ++u) z[u] = (__bf16)0.0f;
    return z;
}

// async global->LDS, 16B per lane; LDS dest is wave-uniform base + lane*16
static __device__ __forceinline__ void gl_lds16(const __bf16* g, __bf16* l) {
    __builtin_amdgcn_global_load_lds(
        (const __attribute__((address_space(1))) void*)g,
        (__attribute__((address_space(3))) void*)l, 16, 0, 0);
}

// ---------------------------------------------------------------------------
// K-1: fp32 -> bf16 bulk convert, 8 elems/thread/iter, grid-stride.
// ---------------------------------------------------------------------------
__global__ __launch_bounds__(256)
void cvt_bf16_k(const float* __restrict__ src, __bf16* __restrict__ dst, int n8)
{
    int i = blockIdx.x * 256 + threadIdx.x;
    const int stride = gridDim.x * 256;
    for (; i < n8; i += stride) {
        float4 a = *reinterpret_cast<const float4*>(src + (size_t)i * 8);
        float4 b = *reinterpret_cast<const float4*>(src + (size_t)i * 8 + 4);
        bf16x8 o;
        o[0] = (__bf16)a.x; o[1] = (__bf16)a.y; o[2] = (__bf16)a.z; o[3] = (__bf16)a.w;
        o[4] = (__bf16)b.x; o[5] = (__bf16)b.y; o[6] = (__bf16)b.z; o[7] = (__bf16)b.w;
        *reinterpret_cast<bf16x8*>(dst + (size_t)i * 8) = o;
    }
}

// ---------------------------------------------------------------------------
// K0: ADD[w*8+h][i][j] = mask[w][i][j] + bias[h][i][j]  (64x64, -1e30 pad)
// ---------------------------------------------------------------------------
__global__ __launch_bounds__(256)
void expand_add_k(const float* __restrict__ mask, const float* __restrict__ rpb,
                  float* __restrict__ add)
{
    const int wh = blockIdx.x;           // 0..511
    const int w = wh >> 3, h = wh & 7;
    for (int e = threadIdx.x; e < 4096; e += 256) {
        int i = e >> 6, j = e & 63;
        float v = -1e30f;
        if (i < 49 && j < 49) {
            int ih = i / 7, iw = i - ih * 7;
            int jh = j / 7, jw = j - jh * 7;
            int bidx = (ih - jh + 6) * 13 + (iw - jw + 6);
            v = mask[(size_t)w * 2401 + i * 49 + j] + rpb[bidx * 8 + h];
        }
        add[(size_t)wh * 4096 + e] = v;
    }
}

// ---------------------------------------------------------------------------
// K1: qkv = xb @ qkv_wb^T + qkv_b -> three (M,256) bf16 segments.
// 128x128 tile, BK=64, 4 waves, dbuf LDS + counted-vmcnt pipeline, T2 XOR
// swizzle (source-preswizzled for global_load_lds; same involution on read).
// Epilogue: n-tile never straddles a 256-col segment -> c3/scale are scalar;
// store address is base + (mt*16+r)*256 (no /49, no head scatter math).
// Grid: flat 9408; XCD-chunked bijective swizzle, n fastest (L2 panel reuse).
// ---------------------------------------------------------------------------
__global__ __launch_bounds__(256)
void qkv_gemm_k(const __bf16* __restrict__ x, const __bf16* __restrict__ w,
                const float* __restrict__ bvec, __bf16* __restrict__ ws)
{
    __shared__ __bf16 As[2][128][64];
    __shared__ __bf16 Bs[2][128][64];
    const int tid  = threadIdx.x;
    const int nwg  = 1568 * 6;                     // 9408, % 8 == 0
    const int bid  = blockIdx.x;
    const int v    = (bid & 7) * (nwg >> 3) + (bid >> 3);
    const int mb   = v / 6, nb = v - mb * 6;
    const int m0   = mb * 128;
    const int n0   = nb * 128;
    const int wave = tid >> 6, lane = tid & 63;
    const int wm   = wave >> 1, wn = wave & 1;
    const int quad = lane >> 4, lm = lane & 15;

    // staging: issue i covers LDS rows [i*32 + wave*8, +8); lane l -> row +l/8,
    // phys col (l&7)*16B. Global col pre-swizzled so phys c16 = logical ^ (row&7).
    const int srow = wave * 8 + (lane >> 3);
    const int scol = (((lane & 7) ^ (lane >> 3)) << 3);   // elems

    f32x4 acc[4][4] = {};

    // prologue: stage tile 0, full drain
#pragma unroll
    for (int i = 0; i < 4; ++i) {
        int row = i * 32 + srow;
        gl_lds16(x + (size_t)(m0 + row) * 256 + 0 + scol,
                 &As[0][0][0] + i * 2048 + wave * 512);
        gl_lds16(w + (size_t)(n0 + row) * 256 + 0 + scol,
                 &Bs[0][0][0] + i * 2048 + wave * 512);
    }
    asm volatile("s_waitcnt vmcnt(0)" ::: "memory");
    __builtin_amdgcn_s_barrier();

#pragma unroll
    for (int t = 0; t < 4; ++t) {
        if (t < 3) {
            const int k0 = (t + 1) * 64;
            const int nb2 = (t + 1) & 1;
#pragma unroll
            for (int i = 0; i < 4; ++i) {
                int row = i * 32 + srow;
                gl_lds16(x + (size_t)(m0 + row) * 256 + k0 + scol,
                         &As[nb2][0][0] + i * 2048 + wave * 512);
                gl_lds16(w + (size_t)(n0 + row) * 256 + k0 + scol,
                         &Bs[nb2][0][0] + i * 2048 + wave * 512);
            }
        }
        const __bf16* Ab = &As[t & 1][0][0];
        const __bf16* Bb = &Bs[t & 1][0][0];
        __builtin_amdgcn_s_setprio(1);
#pragma unroll
        for (int kk = 0; kk < 64; kk += 32) {
            const int cl = (kk >> 3) + quad;      // logical c16
            bf16x8 af[4], bfr[4];
#pragma unroll
            for (int mt = 0; mt < 4; ++mt) {
                int row = wm * 64 + mt * 16 + lm;
                af[mt] = *reinterpret_cast<const bf16x8*>(Ab + row * 64 + ((cl ^ (lm & 7)) << 3));
            }
#pragma unroll
            for (int nt = 0; nt < 4; ++nt) {
                int row = wn * 64 + nt * 16 + lm;
                bfr[nt] = *reinterpret_cast<const bf16x8*>(Bb + row * 64 + ((cl ^ (lm & 7)) << 3));
            }
#pragma unroll
            for (int mt = 0; mt < 4; ++mt)
#pragma unroll
                for (int nt = 0; nt < 4; ++nt)
                    acc[mt][nt] = __builtin_amdgcn_mfma_f32_16x16x32_bf16(af[mt], bfr[nt], acc[mt][nt], 0, 0, 0);
        }
        __builtin_amdgcn_s_setprio(0);
        asm volatile("s_waitcnt vmcnt(0)" ::: "memory");
        __builtin_amdgcn_s_barrier();
    }

    // ---- epilogue: plain (m, c) store into segment c3 = n0>>8 (block-uniform)
    const int   c3   = n0 >> 8;
    const float scl  = (c3 == 0) ? 0.17677669529663687f : 1.0f;
    __bf16*     segp = ws + (size_t)c3 * SEG;
    const int   n0c  = n0 & 255;

#pragma unroll
    for (int nt = 0; nt < 4; ++nt) {
        int   c  = n0c + wn * 64 + nt * 16 + lm;
        float bj = bvec[n0 + wn * 64 + nt * 16 + lm];
        __bf16* p = segp + (size_t)(m0 + wm * 64 + quad * 4) * 256 + c;
#pragma unroll
        for (int mt = 0; mt < 4; ++mt)
#pragma unroll
            for (int r = 0; r < 4; ++r)
                p[(mt * 16 + r) * 256] = (__bf16)((acc[mt][nt][r] + bj) * scl);
    }
}

// ---------------------------------------------------------------------------
// K2: MFMA attention. One wave (64 threads) per (window, head).
//   q/k/v segments are (M,256) with c = h*32+d; row stride 256 elems.
//   S^T = K·Q^T (16 mfma) -> +ADD -> in-register softmax -> P to LDS (bf16)
//   -> out = P·V (16 mfma, V transposed into LDS) -> pre (B_,N,C) bf16.
// ---------------------------------------------------------------------------
__global__ __launch_bounds__(64)
void attn_mfma_k(const __bf16* __restrict__ ws, const float* __restrict__ add,
                 __bf16* __restrict__ pre)
{
    __shared__ __bf16 Pl[64 * 72];   // P[i][j], row stride 72 (2-way bank alias = free)
    __shared__ __bf16 Vt[32 * 72];   // V^T[d][j]
    const int lane = threadIdx.x;
    const int bh   = blockIdx.x;                 // b*8 + h
    const int b    = bh >> 3, h = bh & 7;
    const int wh   = ((b & 63) << 3) | h;
    const int quad = lane >> 4, lm = lane & 15;
    const int koff = quad * 8;

    // row i of this window = global row b*49+i; head column block = h*32
    const __bf16* qp = ws + (size_t)(b * 49) * 256 + h * 32;
    const __bf16* kp = qp + SEG;
    const __bf16* vp = qp + (size_t)2 * SEG;

    // ---- zero V^T pad rows j=48..63 (j=48 overwritten below; j>=49 must be
    // exactly representable-finite so P(=0)*Vt can't make NaN)
    {
        int d = lane >> 1, j0 = 48 + (lane & 1) * 8;
        *reinterpret_cast<bf16x8*>(&Vt[d * 72 + j0]) = bzero8();
    }
    // ---- transpose V (49x32) into Vt
#pragma unroll
    for (int t = 0; t < 4; ++t) {
        int idx = lane + t * 64;
        if (idx < 196) {
            int j = idx >> 2, c8 = (idx & 3) * 8;
            bf16x8 vv = *reinterpret_cast<const bf16x8*>(vp + j * 256 + c8);
#pragma unroll
            for (int u = 0; u < 8; ++u) Vt[(c8 + u) * 72 + j] = vv[u];
        }
    }

    // ---- Q (B-operand, col=i) unpredicated (rows >=49 read into next seg —
    // in-bounds of ws, values never used); K (A-operand, row=j) zero-padded
    bf16x8 qf[4], kf[4];
#pragma unroll
    for (int t = 0; t < 4; ++t)
        qf[t] = *reinterpret_cast<const bf16x8*>(qp + (t * 16 + lm) * 256 + koff);
#pragma unroll
    for (int t = 0; t < 4; ++t) {
        int m = t * 16 + lm;
        kf[t] = (m < 49) ? *reinterpret_cast<const bf16x8*>(kp + m * 256 + koff)
                         : bzero8();
    }

    // ---- S^T = K·Q^T : s[mt][nt], rows j = mt*16+quad*4+r, cols i = nt*16+lm
    f32x4 s[4][4] = {};
#pragma unroll
    for (int mt = 0; mt < 4; ++mt)
#pragma unroll
        for (int nt = 0; nt < 4; ++nt)
            s[mt][nt] = __builtin_amdgcn_mfma_f32_16x16x32_bf16(kf[mt], qf[nt], s[mt][nt], 0, 0, 0);

    // ---- + (mask+bias), layout ADD[wh][i][j]: regs = 4 consecutive j
    const float* ap = add + (size_t)wh * 4096;
#pragma unroll
    for (int nt = 0; nt < 4; ++nt) {
        int i = nt * 16 + lm;
#pragma unroll
        for (int mt = 0; mt < 4; ++mt) {
            f32x4 a4 = *reinterpret_cast<const f32x4*>(ap + i * 64 + mt * 16 + quad * 4);
            s[mt][nt] += a4;
        }
    }

    // ---- softmax over j (rows of S = i). Row i fixed per (nt,lm); j spread
    // over mt, reg, and quad -> in-register reduce + shfl_xor(16,32).
#pragma unroll
    for (int nt = 0; nt < 4; ++nt) {
        float mx = -3.0e38f;
#pragma unroll
        for (int mt = 0; mt < 4; ++mt)
#pragma unroll
            for (int r = 0; r < 4; ++r) mx = fmaxf(mx, s[mt][nt][r]);
        mx = fmaxf(mx, __shfl_xor(mx, 16));
        mx = fmaxf(mx, __shfl_xor(mx, 32));
        float sum = 0.f;
#pragma unroll
        for (int mt = 0; mt < 4; ++mt)
#pragma unroll
            for (int r = 0; r < 4; ++r) {
                float e = __expf(s[mt][nt][r] - mx);
                s[mt][nt][r] = e; sum += e;
            }
        sum += __shfl_xor(sum, 16);
        sum += __shfl_xor(sum, 32);
        float rl = 1.0f / sum;
#pragma unroll
        for (int mt = 0; mt < 4; ++mt)
#pragma unroll
            for (int r = 0; r < 4; ++r) s[mt][nt][r] *= rl;
    }

    // ---- P -> LDS, Pl[i][j]: 4 consecutive j per reg -> b64 stores
#pragma unroll
    for (int nt = 0; nt < 4; ++nt) {
        int i = nt * 16 + lm;
#pragma unroll
        for (int mt = 0; mt < 4; ++mt) {
            bf16x4 p4;
#pragma unroll
            for (int r = 0; r < 4; ++r) p4[r] = (__bf16)s[mt][nt][r];
            *reinterpret_cast<bf16x4*>(&Pl[i * 72 + mt * 16 + quad * 4]) = p4;
        }
    }
    __syncthreads();

    // ---- out = P·V : A = P rows i (ds_read_b128), B = V^T rows d
    f32x4 o[4][2] = {};
#pragma unroll
    for (int kt = 0; kt < 2; ++kt) {
        bf16x8 vf[2];
#pragma unroll
        for (int dt = 0; dt < 2; ++dt)
            vf[dt] = *reinterpret_cast<const bf16x8*>(&Vt[(dt * 16 + lm) * 72 + kt * 32 + koff]);
#pragma unroll
        for (int mt2 = 0; mt2 < 4; ++mt2) {
            bf16x8 pf = *reinterpret_cast<const bf16x8*>(&Pl[(mt2 * 16 + lm) * 72 + kt * 32 + koff]);
#pragma unroll
            for (int dt = 0; dt < 2; ++dt)
                o[mt2][dt] = __builtin_amdgcn_mfma_f32_16x16x32_bf16(pf, vf[dt], o[mt2][dt], 0, 0, 0);
        }
    }

    // ---- store pre (B_,N,C): row i = mt2*16+quad*4+r, col = h*32 + dt*16+lm
#pragma unroll
    for (int mt2 = 0; mt2 < 4; ++mt2) {
        int ib = mt2 * 16 + quad * 4;
#pragma unroll
        for (int r = 0; r < 4; ++r) {
            int i = ib + r;
            if (i < 49) {
                size_t base = ((size_t)(b * 49 + i)) * 256 + h * 32;
                pre[base + lm]      = (__bf16)o[mt2][0][r];
                pre[base + 16 + lm] = (__bf16)o[mt2][1][r];
            }
        }
    }
}

// ---------------------------------------------------------------------------
// K3: out = pre @ proj_wb^T + proj_b (fp32 out). M=200704, K=256, N=256.
// Same dbuf+swizzle structure as K1. Grid: flat 3136, XCD-chunked, n fastest.
// ---------------------------------------------------------------------------
__global__ __launch_bounds__(256)
void proj_gemm_k(const __bf16* __restrict__ pre, const __bf16* __restrict__ w,
                 const float* __restrict__ bvec, float* __restrict__ out)
{
    __shared__ __bf16 As[2][128][64];
    __shared__ __bf16 Bs[2][128][64];
    const int tid  = threadIdx.x;
    const int nwg  = 1568 * 2;                     // 3136, % 8 == 0
    const int bid  = blockIdx.x;
    const int v    = (bid & 7) * (nwg >> 3) + (bid >> 3);
    const int mb   = v >> 1, nb = v & 1;
    const int m0   = mb * 128;
    const int n0   = nb * 128;
    const int wave = tid >> 6, lane = tid & 63;
    const int wm   = wave >> 1, wn = wave & 1;
    const int quad = lane >> 4, lm = lane & 15;

    const int srow = wave * 8 + (lane >> 3);
    const int scol = (((lane & 7) ^ (lane >> 3)) << 3);

    f32x4 acc[4][4] = {};

#pragma unroll
    for (int i = 0; i < 4; ++i) {
        int row = i * 32 + srow;
        gl_lds16(pre + (size_t)(m0 + row) * 256 + 0 + scol,
                 &As[0][0][0] + i * 2048 + wave * 512);
        gl_lds16(w + (size_t)(n0 + row) * 256 + 0 + scol,
                 &Bs[0][0][0] + i * 2048 + wave * 512);
    }
    asm volatile("s_waitcnt vmcnt(0)" ::: "memory");
    __builtin_amdgcn_s_barrier();

#pragma unroll
    for (int t = 0; t < 4; ++t) {
        if (t < 3) {
            const int k0 = (t + 1) * 64;
            const int nb2 = (t + 1) & 1;
#pragma unroll
            for (int i = 0; i < 4; ++i) {
                int row = i * 32 + srow;
                gl_lds16(pre + (size_t)(m0 + row) * 256 + k0 + scol,
                         &As[nb2][0][0] + i * 2048 + wave * 512);
                gl_lds16(w + (size_t)(n0 + row) * 256 + k0 + scol,
                         &Bs[nb2][0][0] + i * 2048 + wave * 512);
            }
        }
        const __bf16* Ab = &As[t & 1][0][0];
        const __bf16* Bb = &Bs[t & 1][0][0];
        __builtin_amdgcn_s_setprio(1);
#pragma unroll
        for (int kk = 0; kk < 64; kk += 32) {
            const int cl = (kk >> 3) + quad;
            bf16x8 af[4], bfr[4];
#pragma unroll
            for (int mt = 0; mt < 4; ++mt) {
                int row = wm * 64 + mt * 16 + lm;
                af[mt] = *reinterpret_cast<const bf16x8*>(Ab + row * 64 + ((cl ^ (lm & 7)) << 3));
            }
#pragma unroll
            for (int nt = 0; nt < 4; ++nt) {
                int row = wn * 64 + nt * 16 + lm;
                bfr[nt] = *reinterpret_cast<const bf16x8*>(Bb + row * 64 + ((cl ^ (lm & 7)) << 3));
            }
#pragma unroll
            for (int mt = 0; mt < 4; ++mt)
#pragma unroll
                for (int nt = 0; nt < 4; ++nt)
                    acc[mt][nt] = __builtin_amdgcn_mfma_f32_16x16x32_bf16(af[mt], bfr[nt], acc[mt][nt], 0, 0, 0);
        }
        __builtin_amdgcn_s_setprio(0);
        asm volatile("s_waitcnt vmcnt(0)" ::: "memory");
        __builtin_amdgcn_s_barrier();
    }

#pragma unroll
    for (int nt = 0; nt < 4; ++nt) {
        int j = n0 + wn*64 + nt*16 + lm;
        float bj = bvec[j];
#pragma unroll
        for (int mt = 0; mt < 4; ++mt)
#pragma unroll
            for (int r = 0; r < 4; ++r) {
                int m = m0 + wm*64 + mt*16 + quad*4 + r;
                out[(size_t)m*256 + j] = acc[mt][nt][r] + bj;
            }
    }
}

extern "C" void kernel_launch(void* const* d_in, const int* in_sizes, int n_in,
                              void* d_out, int out_size, void* d_ws, size_t ws_size,
                              hipStream_t stream)
{
    const float* x      = (const float*)d_in[0];
    const float* mask   = (const float*)d_in[1];
    const float* qkv_w  = (const float*)d_in[2];
    const float* qkv_b  = (const float*)d_in[3];
    const float* proj_w = (const float*)d_in[4];
    const float* proj_b = (const float*)d_in[5];
    const float* rpb    = (const float*)d_in[6];

    __bf16* ws  = (__bf16*)d_ws;                 // 4*SEG*2 = 411 MB
    __bf16* pre = ws + (size_t)3 * SEG;
    float*  out = (float*)d_out;

    char*   ob      = (char*)d_out;
    float*  addbuf  = (float*)ob;                        // [0, 8.39MB)
    __bf16* qkv_wb  = (__bf16*)(ob + (10u << 20));       // 768x256 bf16
    __bf16* xb      = (__bf16*)(ob + (16u << 20));       // 200704x256 bf16, 102.8MB
    __bf16* proj_wb = ws;                                // q segment, dead after attn

    cvt_bf16_k<<<dim3(2048), 256, 0, stream>>>(x, xb, 51380224 / 8);
    cvt_bf16_k<<<dim3(96),   256, 0, stream>>>(qkv_w, qkv_wb, 196608 / 8);
    expand_add_k<<<dim3(512), 256, 0, stream>>>(mask, rpb, addbuf);
    qkv_gemm_k<<<dim3(1568 * 6), 256, 0, stream>>>(xb, qkv_wb, qkv_b, ws);
    attn_mfma_k<<<dim3(32768), 64, 0, stream>>>(ws, addbuf, pre);
    cvt_bf16_k<<<dim3(32),   256, 0, stream>>>(proj_w, proj_wb, 65536 / 8);
    proj_gemm_k<<<dim3(1568 * 2), 256, 0, stream>>>(pre, proj_wb, proj_b, out);
}

// Round 5
// 781.593 us; speedup vs baseline: 1.0166x; 1.0166x over previous
//
#include <hip/hip_runtime.h>

// WindowAttention: B_=4096, N=49, C=256, H=8, hd=32, nW=64
// ws layout (bf16): [q | k | v | pre] each SEG elements
//   q/k/v: plain (M=200704, 256) row-major, m = b*49+i, c = h*32+d
//          (GEMM-natural layout; q pre-scaled by hd^-0.5)
//   pre  : (B_, N, C) attention output before proj
// d_out doubles as scratch:
//   [0, 8.39MB)  : expanded (mask+bias) ADD tensor (nW*H, 64, 64) fp32
//   [10MB, ...)  : qkv_w converted to bf16 (768x256)
//   [16MB, ...)  : x converted to bf16 (200704x256, 102.8MB)
// proj_gemm fully overwrites d_out afterwards and reads none of it.
// proj_w (bf16) is converted AFTER attn into ws segment 0 (q, dead by then).
#define SEG 51380224  // 4096*8*49*32 == 4096*49*256

typedef __attribute__((ext_vector_type(8))) __bf16 bf16x8;
typedef __attribute__((ext_vector_type(4))) __bf16 bf16x4;
typedef __attribute__((ext_vector_type(4))) float f32x4;

static __device__ __forceinline__ bf16x8 bzero8() {
    bf16x8 z;
#pragma unroll
    for (int u = 0; u < 8; ++u) z[u] = (__bf16)0.0f;
    return z;
}

// async global->LDS, 16B per lane; LDS dest is wave-uniform base + lane*16
static __device__ __forceinline__ void gl_lds16(const __bf16* g, __bf16* l) {
    __builtin_amdgcn_global_load_lds(
        (const __attribute__((address_space(1))) void*)g,
        (__attribute__((address_space(3))) void*)l, 16, 0, 0);
}

// ---------------------------------------------------------------------------
// K-1: fp32 -> bf16 bulk convert, 8 elems/thread/iter, grid-stride.
// ---------------------------------------------------------------------------
__global__ __launch_bounds__(256)
void cvt_bf16_k(const float* __restrict__ src, __bf16* __restrict__ dst, int n8)
{
    int i = blockIdx.x * 256 + threadIdx.x;
    const int stride = gridDim.x * 256;
    for (; i < n8; i += stride) {
        float4 a = *reinterpret_cast<const float4*>(src + (size_t)i * 8);
        float4 b = *reinterpret_cast<const float4*>(src + (size_t)i * 8 + 4);
        bf16x8 o;
        o[0] = (__bf16)a.x; o[1] = (__bf16)a.y; o[2] = (__bf16)a.z; o[3] = (__bf16)a.w;
        o[4] = (__bf16)b.x; o[5] = (__bf16)b.y; o[6] = (__bf16)b.z; o[7] = (__bf16)b.w;
        *reinterpret_cast<bf16x8*>(dst + (size_t)i * 8) = o;
    }
}

// ---------------------------------------------------------------------------
// K0: ADD[w*8+h][i][j] = mask[w][i][j] + bias[h][i][j]  (64x64, -1e30 pad)
// ---------------------------------------------------------------------------
__global__ __launch_bounds__(256)
void expand_add_k(const float* __restrict__ mask, const float* __restrict__ rpb,
                  float* __restrict__ add)
{
    const int wh = blockIdx.x;           // 0..511
    const int w = wh >> 3, h = wh & 7;
    for (int e = threadIdx.x; e < 4096; e += 256) {
        int i = e >> 6, j = e & 63;
        float v = -1e30f;
        if (i < 49 && j < 49) {
            int ih = i / 7, iw = i - ih * 7;
            int jh = j / 7, jw = j - jh * 7;
            int bidx = (ih - jh + 6) * 13 + (iw - jw + 6);
            v = mask[(size_t)w * 2401 + i * 49 + j] + rpb[bidx * 8 + h];
        }
        add[(size_t)wh * 4096 + e] = v;
    }
}

// ---------------------------------------------------------------------------
// K1: qkv = xb @ qkv_wb^T + qkv_b -> three (M,256) bf16 segments.
// 128x128 tile, BK=64, 4 waves, dbuf LDS + counted-vmcnt pipeline, T2 XOR
// swizzle on staging. Epilogue: C restaged through LDS (reuse As, 32KB,
// XOR (row&0xC)<<2 on byte addr) -> coalesced bf16x8 stores: 256B contiguous
// segments (full sectors) instead of scattered 2B/lane (32B partial sectors).
// Grid: flat 9408; XCD-chunked bijective swizzle, n fastest (L2 panel reuse).
// ---------------------------------------------------------------------------
__global__ __launch_bounds__(256)
void qkv_gemm_k(const __bf16* __restrict__ x, const __bf16* __restrict__ w,
                const float* __restrict__ bvec, __bf16* __restrict__ ws)
{
    __shared__ __bf16 As[2][128][64];
    __shared__ __bf16 Bs[2][128][64];
    const int tid  = threadIdx.x;
    const int nwg  = 1568 * 6;                     // 9408, % 8 == 0
    const int bid  = blockIdx.x;
    const int v    = (bid & 7) * (nwg >> 3) + (bid >> 3);
    const int mb   = v / 6, nb = v - mb * 6;
    const int m0   = mb * 128;
    const int n0   = nb * 128;
    const int wave = tid >> 6, lane = tid & 63;
    const int wm   = wave >> 1, wn = wave & 1;
    const int quad = lane >> 4, lm = lane & 15;

    // staging: issue i covers LDS rows [i*32 + wave*8, +8); lane l -> row +l/8,
    // phys col (l&7)*16B. Global col pre-swizzled so phys c16 = logical ^ (row&7).
    const int srow = wave * 8 + (lane >> 3);
    const int scol = (((lane & 7) ^ (lane >> 3)) << 3);   // elems

    f32x4 acc[4][4] = {};

    // prologue: stage tile 0, full drain
#pragma unroll
    for (int i = 0; i < 4; ++i) {
        int row = i * 32 + srow;
        gl_lds16(x + (size_t)(m0 + row) * 256 + 0 + scol,
                 &As[0][0][0] + i * 2048 + wave * 512);
        gl_lds16(w + (size_t)(n0 + row) * 256 + 0 + scol,
                 &Bs[0][0][0] + i * 2048 + wave * 512);
    }
    asm volatile("s_waitcnt vmcnt(0)" ::: "memory");
    __builtin_amdgcn_s_barrier();

#pragma unroll
    for (int t = 0; t < 4; ++t) {
        if (t < 3) {
            const int k0 = (t + 1) * 64;
            const int nb2 = (t + 1) & 1;
#pragma unroll
            for (int i = 0; i < 4; ++i) {
                int row = i * 32 + srow;
                gl_lds16(x + (size_t)(m0 + row) * 256 + k0 + scol,
                         &As[nb2][0][0] + i * 2048 + wave * 512);
                gl_lds16(w + (size_t)(n0 + row) * 256 + k0 + scol,
                         &Bs[nb2][0][0] + i * 2048 + wave * 512);
            }
        }
        const __bf16* Ab = &As[t & 1][0][0];
        const __bf16* Bb = &Bs[t & 1][0][0];
        __builtin_amdgcn_s_setprio(1);
#pragma unroll
        for (int kk = 0; kk < 64; kk += 32) {
            const int cl = (kk >> 3) + quad;      // logical c16
            bf16x8 af[4], bfr[4];
#pragma unroll
            for (int mt = 0; mt < 4; ++mt) {
                int row = wm * 64 + mt * 16 + lm;
                af[mt] = *reinterpret_cast<const bf16x8*>(Ab + row * 64 + ((cl ^ (lm & 7)) << 3));
            }
#pragma unroll
            for (int nt = 0; nt < 4; ++nt) {
                int row = wn * 64 + nt * 16 + lm;
                bfr[nt] = *reinterpret_cast<const bf16x8*>(Bb + row * 64 + ((cl ^ (lm & 7)) << 3));
            }
#pragma unroll
            for (int mt = 0; mt < 4; ++mt)
#pragma unroll
                for (int nt = 0; nt < 4; ++nt)
                    acc[mt][nt] = __builtin_amdgcn_mfma_f32_16x16x32_bf16(af[mt], bfr[nt], acc[mt][nt], 0, 0, 0);
        }
        __builtin_amdgcn_s_setprio(0);
        asm volatile("s_waitcnt vmcnt(0)" ::: "memory");
        __builtin_amdgcn_s_barrier();
    }

    // ---- epilogue: restage C tile (bf16) through LDS, then coalesced stores.
    // Cs = As reuse: 128 rows x 256B stride = 32KB exactly; XOR (row&0xC)<<2
    // puts each quad's 16 scalar writes in a distinct 16B window (no 8-way).
    const int   c3   = n0 >> 8;
    const float scl  = (c3 == 0) ? 0.17677669529663687f : 1.0f;
    __bf16*     segp = ws + (size_t)c3 * SEG;
    const int   n0c  = n0 & 255;
    char*       Cs   = (char*)&As[0][0][0];

#pragma unroll
    for (int nt = 0; nt < 4; ++nt) {
        float bj = bvec[n0 + wn * 64 + nt * 16 + lm];
#pragma unroll
        for (int mt = 0; mt < 4; ++mt)
#pragma unroll
            for (int r = 0; r < 4; ++r) {
                int row = wm * 64 + mt * 16 + quad * 4 + r;
                int byteoff = (row << 8) + ((wn * 64 + nt * 16 + lm) << 1);
                byteoff ^= (row & 0xC) << 2;
                *reinterpret_cast<__bf16*>(Cs + byteoff) =
                    (__bf16)((acc[mt][nt][r] + bj) * scl);
            }
    }
    __syncthreads();
    // 16 lanes x 16B = 256B contiguous per row, 4 rows per wave-instr
#pragma unroll
    for (int it = 0; it < 8; ++it) {
        int row = it * 16 + (tid >> 4);
        int byteoff = (row << 8) + ((tid & 15) << 4);
        byteoff ^= (row & 0xC) << 2;
        bf16x8 c8 = *reinterpret_cast<const bf16x8*>(Cs + byteoff);
        *reinterpret_cast<bf16x8*>(segp + (size_t)(m0 + row) * 256 + n0c + ((tid & 15) << 3)) = c8;
    }
}

// ---------------------------------------------------------------------------
// K2: MFMA attention. One wave (64 threads) per (window, head).
//   q/k/v segments are (M,256) with c = h*32+d; row stride 256 elems.
//   S^T = K·Q^T (16 mfma) -> +ADD -> in-register softmax -> P to LDS (bf16)
//   -> out = P·V (16 mfma, V transposed into LDS) -> restage O via LDS ->
//   coalesced 64B-segment stores to pre (B_,N,C) bf16.
// ---------------------------------------------------------------------------
__global__ __launch_bounds__(64)
void attn_mfma_k(const __bf16* __restrict__ ws, const float* __restrict__ add,
                 __bf16* __restrict__ pre)
{
    __shared__ __bf16 Pl[64 * 72];   // P[i][j], row stride 72 (2-way bank alias = free)
    __shared__ __bf16 Vt[32 * 72];   // V^T[d][j]; reused as O[64][32] at the end
    const int lane = threadIdx.x;
    const int bh   = blockIdx.x;                 // b*8 + h
    const int b    = bh >> 3, h = bh & 7;
    const int wh   = ((b & 63) << 3) | h;
    const int quad = lane >> 4, lm = lane & 15;
    const int koff = quad * 8;

    // row i of this window = global row b*49+i; head column block = h*32
    const __bf16* qp = ws + (size_t)(b * 49) * 256 + h * 32;
    const __bf16* kp = qp + SEG;
    const __bf16* vp = qp + (size_t)2 * SEG;

    // ---- zero V^T pad rows j=48..63 (j=48 overwritten below; j>=49 must be
    // exactly representable-finite so P(=0)*Vt can't make NaN)
    {
        int d = lane >> 1, j0 = 48 + (lane & 1) * 8;
        *reinterpret_cast<bf16x8*>(&Vt[d * 72 + j0]) = bzero8();
    }
    // ---- transpose V (49x32) into Vt
#pragma unroll
    for (int t = 0; t < 4; ++t) {
        int idx = lane + t * 64;
        if (idx < 196) {
            int j = idx >> 2, c8 = (idx & 3) * 8;
            bf16x8 vv = *reinterpret_cast<const bf16x8*>(vp + j * 256 + c8);
#pragma unroll
            for (int u = 0; u < 8; ++u) Vt[(c8 + u) * 72 + j] = vv[u];
        }
    }

    // ---- Q (B-operand, col=i) unpredicated (rows >=49 read into next seg —
    // in-bounds of ws, values never used); K (A-operand, row=j) zero-padded
    bf16x8 qf[4], kf[4];
#pragma unroll
    for (int t = 0; t < 4; ++t)
        qf[t] = *reinterpret_cast<const bf16x8*>(qp + (t * 16 + lm) * 256 + koff);
#pragma unroll
    for (int t = 0; t < 4; ++t) {
        int m = t * 16 + lm;
        kf[t] = (m < 49) ? *reinterpret_cast<const bf16x8*>(kp + m * 256 + koff)
                         : bzero8();
    }

    // ---- S^T = K·Q^T : s[mt][nt], rows j = mt*16+quad*4+r, cols i = nt*16+lm
    f32x4 s[4][4] = {};
#pragma unroll
    for (int mt = 0; mt < 4; ++mt)
#pragma unroll
        for (int nt = 0; nt < 4; ++nt)
            s[mt][nt] = __builtin_amdgcn_mfma_f32_16x16x32_bf16(kf[mt], qf[nt], s[mt][nt], 0, 0, 0);

    // ---- + (mask+bias), layout ADD[wh][i][j]: regs = 4 consecutive j
    const float* ap = add + (size_t)wh * 4096;
#pragma unroll
    for (int nt = 0; nt < 4; ++nt) {
        int i = nt * 16 + lm;
#pragma unroll
        for (int mt = 0; mt < 4; ++mt) {
            f32x4 a4 = *reinterpret_cast<const f32x4*>(ap + i * 64 + mt * 16 + quad * 4);
            s[mt][nt] += a4;
        }
    }

    // ---- softmax over j (rows of S = i). Row i fixed per (nt,lm); j spread
    // over mt, reg, and quad -> in-register reduce + shfl_xor(16,32).
#pragma unroll
    for (int nt = 0; nt < 4; ++nt) {
        float mx = -3.0e38f;
#pragma unroll
        for (int mt = 0; mt < 4; ++mt)
#pragma unroll
            for (int r = 0; r < 4; ++r) mx = fmaxf(mx, s[mt][nt][r]);
        mx = fmaxf(mx, __shfl_xor(mx, 16));
        mx = fmaxf(mx, __shfl_xor(mx, 32));
        float sum = 0.f;
#pragma unroll
        for (int mt = 0; mt < 4; ++mt)
#pragma unroll
            for (int r = 0; r < 4; ++r) {
                float e = __expf(s[mt][nt][r] - mx);
                s[mt][nt][r] = e; sum += e;
            }
        sum += __shfl_xor(sum, 16);
        sum += __shfl_xor(sum, 32);
        float rl = 1.0f / sum;
#pragma unroll
        for (int mt = 0; mt < 4; ++mt)
#pragma unroll
            for (int r = 0; r < 4; ++r) s[mt][nt][r] *= rl;
    }

    // ---- P -> LDS, Pl[i][j]: 4 consecutive j per reg -> b64 stores
#pragma unroll
    for (int nt = 0; nt < 4; ++nt) {
        int i = nt * 16 + lm;
#pragma unroll
        for (int mt = 0; mt < 4; ++mt) {
            bf16x4 p4;
#pragma unroll
            for (int r = 0; r < 4; ++r) p4[r] = (__bf16)s[mt][nt][r];
            *reinterpret_cast<bf16x4*>(&Pl[i * 72 + mt * 16 + quad * 4]) = p4;
        }
    }
    __syncthreads();

    // ---- out = P·V : A = P rows i (ds_read_b128), B = V^T rows d
    f32x4 o[4][2] = {};
#pragma unroll
    for (int kt = 0; kt < 2; ++kt) {
        bf16x8 vf[2];
#pragma unroll
        for (int dt = 0; dt < 2; ++dt)
            vf[dt] = *reinterpret_cast<const bf16x8*>(&Vt[(dt * 16 + lm) * 72 + kt * 32 + koff]);
#pragma unroll
        for (int mt2 = 0; mt2 < 4; ++mt2) {
            bf16x8 pf = *reinterpret_cast<const bf16x8*>(&Pl[(mt2 * 16 + lm) * 72 + kt * 32 + koff]);
#pragma unroll
            for (int dt = 0; dt < 2; ++dt)
                o[mt2][dt] = __builtin_amdgcn_mfma_f32_16x16x32_bf16(pf, vf[dt], o[mt2][dt], 0, 0, 0);
        }
    }

    // ---- restage O through LDS (reuse Vt as [64][32]) -> coalesced stores:
    // 4 lanes x 16B = 64B contiguous (full sector) per row, 16 rows per instr.
    __syncthreads();                     // all Vt reads complete before reuse
    __bf16* Ol = &Vt[0];
#pragma unroll
    for (int mt2 = 0; mt2 < 4; ++mt2)
#pragma unroll
        for (int dt = 0; dt < 2; ++dt)
#pragma unroll
            for (int r = 0; r < 4; ++r)
                Ol[(mt2 * 16 + quad * 4 + r) * 32 + dt * 16 + lm] = (__bf16)o[mt2][dt][r];
    __syncthreads();
#pragma unroll
    for (int it = 0; it < 4; ++it) {
        int i = it * 16 + (lane >> 2);
        if (i < 49) {
            bf16x8 v8 = *reinterpret_cast<const bf16x8*>(&Ol[i * 32 + (lane & 3) * 8]);
            *reinterpret_cast<bf16x8*>(pre + ((size_t)(b * 49 + i)) * 256 + h * 32 + (lane & 3) * 8) = v8;
        }
    }
}

// ---------------------------------------------------------------------------
// K3: out = pre @ proj_wb^T + proj_b (fp32 out). M=200704, K=256, N=256.
// Same dbuf+swizzle structure as K1. fp32 stores already cover full 64B
// sectors (16 lanes x 4B). Grid: flat 3136, XCD-chunked, n fastest.
// ---------------------------------------------------------------------------
__global__ __launch_bounds__(256)
void proj_gemm_k(const __bf16* __restrict__ pre, const __bf16* __restrict__ w,
                 const float* __restrict__ bvec, float* __restrict__ out)
{
    __shared__ __bf16 As[2][128][64];
    __shared__ __bf16 Bs[2][128][64];
    const int tid  = threadIdx.x;
    const int nwg  = 1568 * 2;                     // 3136, % 8 == 0
    const int bid  = blockIdx.x;
    const int v    = (bid & 7) * (nwg >> 3) + (bid >> 3);
    const int mb   = v >> 1, nb = v & 1;
    const int m0   = mb * 128;
    const int n0   = nb * 128;
    const int wave = tid >> 6, lane = tid & 63;
    const int wm   = wave >> 1, wn = wave & 1;
    const int quad = lane >> 4, lm = lane & 15;

    const int srow = wave * 8 + (lane >> 3);
    const int scol = (((lane & 7) ^ (lane >> 3)) << 3);

    f32x4 acc[4][4] = {};

#pragma unroll
    for (int i = 0; i < 4; ++i) {
        int row = i * 32 + srow;
        gl_lds16(pre + (size_t)(m0 + row) * 256 + 0 + scol,
                 &As[0][0][0] + i * 2048 + wave * 512);
        gl_lds16(w + (size_t)(n0 + row) * 256 + 0 + scol,
                 &Bs[0][0][0] + i * 2048 + wave * 512);
    }
    asm volatile("s_waitcnt vmcnt(0)" ::: "memory");
    __builtin_amdgcn_s_barrier();

#pragma unroll
    for (int t = 0; t < 4; ++t) {
        if (t < 3) {
            const int k0 = (t + 1) * 64;
            const int nb2 = (t + 1) & 1;
#pragma unroll
            for (int i = 0; i < 4; ++i) {
                int row = i * 32 + srow;
                gl_lds16(pre + (size_t)(m0 + row) * 256 + k0 + scol,
                         &As[nb2][0][0] + i * 2048 + wave * 512);
                gl_lds16(w + (size_t)(n0 + row) * 256 + k0 + scol,
                         &Bs[nb2][0][0] + i * 2048 + wave * 512);
            }
        }
        const __bf16* Ab = &As[t & 1][0][0];
        const __bf16* Bb = &Bs[t & 1][0][0];
        __builtin_amdgcn_s_setprio(1);
#pragma unroll
        for (int kk = 0; kk < 64; kk += 32) {
            const int cl = (kk >> 3) + quad;
            bf16x8 af[4], bfr[4];
#pragma unroll
            for (int mt = 0; mt < 4; ++mt) {
                int row = wm * 64 + mt * 16 + lm;
                af[mt] = *reinterpret_cast<const bf16x8*>(Ab + row * 64 + ((cl ^ (lm & 7)) << 3));
            }
#pragma unroll
            for (int nt = 0; nt < 4; ++nt) {
                int row = wn * 64 + nt * 16 + lm;
                bfr[nt] = *reinterpret_cast<const bf16x8*>(Bb + row * 64 + ((cl ^ (lm & 7)) << 3));
            }
#pragma unroll
            for (int mt = 0; mt < 4; ++mt)
#pragma unroll
                for (int nt = 0; nt < 4; ++nt)
                    acc[mt][nt] = __builtin_amdgcn_mfma_f32_16x16x32_bf16(af[mt], bfr[nt], acc[mt][nt], 0, 0, 0);
        }
        __builtin_amdgcn_s_setprio(0);
        asm volatile("s_waitcnt vmcnt(0)" ::: "memory");
        __builtin_amdgcn_s_barrier();
    }

#pragma unroll
    for (int nt = 0; nt < 4; ++nt) {
        int j = n0 + wn*64 + nt*16 + lm;
        float bj = bvec[j];
#pragma unroll
        for (int mt = 0; mt < 4; ++mt)
#pragma unroll
            for (int r = 0; r < 4; ++r) {
                int m = m0 + wm*64 + mt*16 + quad*4 + r;
                out[(size_t)m*256 + j] = acc[mt][nt][r] + bj;
            }
    }
}

extern "C" void kernel_launch(void* const* d_in, const int* in_sizes, int n_in,
                              void* d_out, int out_size, void* d_ws, size_t ws_size,
                              hipStream_t stream)
{
    const float* x      = (const float*)d_in[0];
    const float* mask   = (const float*)d_in[1];
    const float* qkv_w  = (const float*)d_in[2];
    const float* qkv_b  = (const float*)d_in[3];
    const float* proj_w = (const float*)d_in[4];
    const float* proj_b = (const float*)d_in[5];
    const float* rpb    = (const float*)d_in[6];

    __bf16* ws  = (__bf16*)d_ws;                 // 4*SEG*2 = 411 MB
    __bf16* pre = ws + (size_t)3 * SEG;
    float*  out = (float*)d_out;

    char*   ob      = (char*)d_out;
    float*  addbuf  = (float*)ob;                        // [0, 8.39MB)
    __bf16* qkv_wb  = (__bf16*)(ob + (10u << 20));       // 768x256 bf16
    __bf16* xb      = (__bf16*)(ob + (16u << 20));       // 200704x256 bf16, 102.8MB
    __bf16* proj_wb = ws;                                // q segment, dead after attn

    cvt_bf16_k<<<dim3(2048), 256, 0, stream>>>(x, xb, 51380224 / 8);
    cvt_bf16_k<<<dim3(96),   256, 0, stream>>>(qkv_w, qkv_wb, 196608 / 8);
    expand_add_k<<<dim3(512), 256, 0, stream>>>(mask, rpb, addbuf);
    qkv_gemm_k<<<dim3(1568 * 6), 256, 0, stream>>>(xb, qkv_wb, qkv_b, ws);
    attn_mfma_k<<<dim3(32768), 64, 0, stream>>>(ws, addbuf, pre);
    cvt_bf16_k<<<dim3(32),   256, 0, stream>>>(proj_w, proj_wb, 65536 / 8);
    proj_gemm_k<<<dim3(1568 * 2), 256, 0, stream>>>(pre, proj_wb, proj_b, out);
}